// Round 13
// baseline (142.307 us; speedup 1.0000x reference)
//
#include <hip/hip_runtime.h>
#include <cstdint>
#include <cstddef>

#define BQ   4
#define CQ   64
#define GH   128
#define GW   512
#define SWW  512
#define HALF 256
#define HWQ  (GH * GW)        // 65536
#define NPIX (BQ * HWQ)       // 262144
#define NSEG (BQ * SWW * SWW) // 1048576

// Monotone order-preserving f32 -> u32 map: encoded compare == float compare.
__device__ __forceinline__ unsigned ord_encode(float f) {
    unsigned b = __float_as_uint(f);
    return (b & 0x80000000u) ? ~b : (b | 0x80000000u);
}

__global__ void k_init(unsigned* __restrict__ seg, int* __restrict__ winner) {
    int i = blockIdx.x * blockDim.x + threadIdx.x; // exactly NSEG threads
    seg[i] = 0xFF800000u;  // ord_encode(+inf): identity for MIN
    winner[i] = -1;
}

// R13 (candidate E): reference divides via RECIPROCAL-MULTIPLY:
//   inv = rn32(1/mpp) = 5.0f exactly;  bin = trunc(x3 * inv)
// Evidence chain: ref == pure-f32 at pixel q (any f64 anywhere flips q ->
// 3.0625); ref != pure-f32 at exactly one pixel p at a kept/bin boundary
// (beacon: ref-filled, me-empty -> 2.6875). The only untested f32-level
// division variant is mul-by-reciprocal -- the natural hand-optimized np
// idiom (and XLA div->mul simplification). rn(x3*5.0) differs from
// rn(x3/0.20000000298) by ~1ulp at bin boundaries: flips p, not q.
__global__ void k_project(const float* __restrict__ ck,
                          const float* __restrict__ depth,
                          const float* __restrict__ mppp,
                          int* __restrict__ cellArr,
                          float* __restrict__ yArr) {
#pragma clang fp contract(off)
    int i = blockIdx.x * blockDim.x + threadIdx.x; // exactly NPIX threads
    int b   = i >> 16;       // / HWQ
    int rem = i & (HWQ - 1);
    int v   = rem >> 9;      // / GW
    int u   = rem & (GW - 1);

    const float* K = ck + b * 9;
    float K00 = K[0] * 0.5f;           // exact (250)
    float K02 = K[2] * 0.5f;           // exact (256)
    float K11 = K[4] * 0.5f;           // exact (250)
    float K12 = K[5] * 0.5f;           // exact (64)
    float Ki00 = 1.0f / K00;           // rn(1/250) -- pinned by pow2 structure
    float Ki02 = (-K02) / K00;         // rn(-256/250)
    float Ki11 = 1.0f / K11;
    float Ki12 = (-K12) / K11;

    float d   = depth[i];
    float mpp = mppp[0];

    // unfused f32 mul+add (asm barrier blocks fma contraction)
    float tx = Ki00 * (float)u;
    asm volatile("" : "+v"(tx));
    float xw = tx + Ki02;
    float ty = Ki11 * (float)v;
    asm volatile("" : "+v"(ty));
    float yw = ty + Ki12;

    float x3 = (xw * d) * 1.2f;        // left-assoc f32 (reference text order)
    float y3 = (yw * d) * 1.2f;
    float z3 = d * 1.2f;               // zw == 1 exactly

    // ---- THE CHANGE: reciprocal-multiply instead of divide ----
    float r = 1.0f / mpp;              // rn32(1/0.2f) == 5.0f exactly
    asm volatile("" : "+v"(r));        // keep it a separate rounding step
    float x = truncf(x3 * r);
    float z = truncf(z3 * r);

    bool kept = (x >= -(float)HALF) && (x <= (float)(HALF - 1)) &&
                (z >= -(float)HALF) && (z <= (float)(HALF - 1));

    int cell = -1;
    if (kept) cell = b * (SWW * SWW) + ((int)x + HALF) * SWW + ((int)z + HALF);

    cellArr[i] = cell;
    yArr[i]    = y3;
}

// Exact-y segment MIN (winner ordering == argmax hkey; proven key-variant
// invariant across r2/r9).
__global__ void k_segmin(const int* __restrict__ cellArr,
                         const float* __restrict__ yArr,
                         unsigned* __restrict__ seg) {
    int i = blockIdx.x * blockDim.x + threadIdx.x;
    int cell = cellArr[i];
    if (cell >= 0) atomicMin(seg + cell, ord_encode(yArr[i]));
}

// Winner = bit-equal y-min; exact ties -> last-wins (np sequential scatter).
__global__ void k_winner(const int* __restrict__ cellArr,
                         const float* __restrict__ yArr,
                         const unsigned* __restrict__ seg,
                         int* __restrict__ winner) {
    int i = blockIdx.x * blockDim.x + threadIdx.x;
    int cell = cellArr[i];
    if (cell >= 0) {
        if (ord_encode(yArr[i]) == seg[cell]) atomicMax(&winner[cell], i);
    }
}

// One block per (b, xi) row; 512 threads = zi. Winner id stays in a register
// across the 64-channel loop; output writes fully coalesced (2 KB/row/chan).
__global__ void __launch_bounds__(512) k_emit(const int* __restrict__ winner,
                                              const float* __restrict__ img,
                                              float* __restrict__ out) {
    int bid = blockIdx.x;        // BQ*SWW blocks
    int b   = bid >> 9;
    int xi  = bid & (SWW - 1);
    int zi  = threadIdx.x;

    int pid = winner[(b * SWW + xi) * SWW + zi];
    int src = -1;
    if (pid >= 0) src = b * (CQ * HWQ) + (pid & (HWQ - 1));

    float* op = out + ((size_t)(b * CQ) * SWW + xi) * SWW + zi;
    #pragma unroll 4
    for (int c = 0; c < CQ; ++c) {
        float val = (src >= 0) ? img[src + c * HWQ] : 0.0f;
        op[(size_t)c * SWW * SWW] = val;
    }
}

extern "C" void kernel_launch(void* const* d_in, const int* in_sizes, int n_in,
                              void* d_out, int out_size, void* d_ws, size_t ws_size,
                              hipStream_t stream) {
    const float* img   = (const float*)d_in[0];
    const float* ck    = (const float*)d_in[1];
    const float* depth = (const float*)d_in[2];
    const float* mpp   = (const float*)d_in[3];
    float* out = (float*)d_out;

    char* ws = (char*)d_ws;
    unsigned* seg    = (unsigned*)(ws + 256);                      // NSEG * 4
    int*      winner = (int*)(ws + 256 + (size_t)NSEG * 4);        // NSEG * 4
    int*      cellA  = (int*)(ws + 256 + (size_t)NSEG * 8);        // NPIX * 4
    float*    yA     = (float*)(ws + 256 + (size_t)NSEG * 8 + (size_t)NPIX * 4); // NPIX*4

    k_init   <<<NSEG / 256, 256, 0, stream>>>(seg, winner);
    k_project<<<NPIX / 256, 256, 0, stream>>>(ck, depth, mpp, cellA, yA);
    k_segmin <<<NPIX / 256, 256, 0, stream>>>(cellA, yA, seg);
    k_winner <<<NPIX / 256, 256, 0, stream>>>(cellA, yA, seg, winner);
    k_emit   <<<BQ * SWW, 512, 0, stream>>>(winner, img, out);
}

// Round 14
// 122.282 us; speedup vs baseline: 1.1638x; 1.1638x over previous
//
#include <hip/hip_runtime.h>
#include <cstdint>
#include <cstddef>

#define BQ   4
#define CQ   64
#define GH   128
#define GW   512
#define SWW  512
#define HALF 256
#define HWQ  (GH * GW)        // 65536
#define NPIX (BQ * HWQ)       // 262144
#define NSEG (BQ * SWW * SWW) // 1048576

// Monotone order-preserving f32 -> u32 map: encoded compare == float compare.
__device__ __forceinline__ unsigned ord_encode(float f) {
    unsigned b = __float_as_uint(f);
    return (b & 0x80000000u) ? ~b : (b | 0x80000000u);
}

__global__ void k_init(unsigned* __restrict__ seg, int* __restrict__ winner) {
    int i = blockIdx.x * blockDim.x + threadIdx.x; // exactly NSEG threads
    seg[i] = 0xFF800000u;  // ord_encode(+inf): identity for MIN
    winner[i] = -1;
}

// PASSED r13 chain: f32 throughout, reciprocal-multiply binning
// (inv = rn32(1/mpp); bin = trunc(x3*inv)) -- DO NOT TOUCH.
__global__ void k_project(const float* __restrict__ ck,
                          const float* __restrict__ depth,
                          const float* __restrict__ mppp,
                          int* __restrict__ cellArr,
                          float* __restrict__ yArr) {
#pragma clang fp contract(off)
    int i = blockIdx.x * blockDim.x + threadIdx.x; // exactly NPIX threads
    int b   = i >> 16;       // / HWQ
    int rem = i & (HWQ - 1);
    int v   = rem >> 9;      // / GW
    int u   = rem & (GW - 1);

    const float* K = ck + b * 9;
    float K00 = K[0] * 0.5f;           // exact (250)
    float K02 = K[2] * 0.5f;           // exact (256)
    float K11 = K[4] * 0.5f;           // exact (250)
    float K12 = K[5] * 0.5f;           // exact (64)
    float Ki00 = 1.0f / K00;
    float Ki02 = (-K02) / K00;
    float Ki11 = 1.0f / K11;
    float Ki12 = (-K12) / K11;

    float d   = depth[i];
    float mpp = mppp[0];

    float tx = Ki00 * (float)u;
    asm volatile("" : "+v"(tx));
    float xw = tx + Ki02;
    float ty = Ki11 * (float)v;
    asm volatile("" : "+v"(ty));
    float yw = ty + Ki12;

    float x3 = (xw * d) * 1.2f;
    float y3 = (yw * d) * 1.2f;
    float z3 = d * 1.2f;

    float r = 1.0f / mpp;              // rn32(1/0.2f) == 5.0f exactly
    asm volatile("" : "+v"(r));
    float x = truncf(x3 * r);
    float z = truncf(z3 * r);

    bool kept = (x >= -(float)HALF) && (x <= (float)(HALF - 1)) &&
                (z >= -(float)HALF) && (z <= (float)(HALF - 1));

    int cell = -1;
    if (kept) cell = b * (SWW * SWW) + ((int)x + HALF) * SWW + ((int)z + HALF);

    cellArr[i] = cell;
    yArr[i]    = y3;
}

__global__ void k_segmin(const int* __restrict__ cellArr,
                         const float* __restrict__ yArr,
                         unsigned* __restrict__ seg) {
    int i = blockIdx.x * blockDim.x + threadIdx.x;
    int cell = cellArr[i];
    if (cell >= 0) atomicMin(seg + cell, ord_encode(yArr[i]));
}

__global__ void k_winner(const int* __restrict__ cellArr,
                         const float* __restrict__ yArr,
                         const unsigned* __restrict__ seg,
                         int* __restrict__ winner) {
    int i = blockIdx.x * blockDim.x + threadIdx.x;
    int cell = cellArr[i];
    if (cell >= 0) {
        if (ord_encode(yArr[i]) == seg[cell]) atomicMax(&winner[cell], i);
    }
}

// img [b][c][p] -> T [b][p][c]: classic LDS tile transpose, 64c x 64p tiles,
// float4 on both global sides. 134 MB total, fully coalesced.
__global__ void __launch_bounds__(256) k_transpose(const float* __restrict__ img,
                                                   float* __restrict__ T) {
    __shared__ float lds[64][65];
    int b  = blockIdx.y;
    int p0 = blockIdx.x * 64;
    int t  = threadIdx.x;

    const float4* img4 = (const float4*)img;
    #pragma unroll
    for (int iter = 0; iter < 4; ++iter) {
        int idx = iter * 256 + t;          // 64c x 16p4
        int c   = idx >> 4;
        int p4  = idx & 15;
        float4 v = img4[((size_t)(b * CQ + c) * HWQ + p0) / 4 + p4];
        lds[c][p4 * 4 + 0] = v.x;
        lds[c][p4 * 4 + 1] = v.y;
        lds[c][p4 * 4 + 2] = v.z;
        lds[c][p4 * 4 + 3] = v.w;
    }
    __syncthreads();
    float4* T4 = (float4*)T;
    #pragma unroll
    for (int iter = 0; iter < 4; ++iter) {
        int idx = iter * 256 + t;          // 64p x 16c4
        int p   = idx >> 4;
        int c4  = idx & 15;
        float4 v;
        v.x = lds[c4 * 4 + 0][p];
        v.y = lds[c4 * 4 + 1][p];
        v.z = lds[c4 * 4 + 2][p];
        v.w = lds[c4 * 4 + 3][p];
        T4[(size_t)(b * HWQ + p0 + p) * 16 + c4] = v;
    }
}

// One block per (b, xi) row. Per 128-cell chunk: gather winner feature
// vectors as CONTIGUOUS 256B blocks from T (16 thr x float4 per cell),
// stage in LDS, then write out coalesced in [c][zi] order.
__global__ void __launch_bounds__(512) k_emit2(const int* __restrict__ winner,
                                               const float* __restrict__ T,
                                               float* __restrict__ out) {
    __shared__ float lds[128][68];   // [cell][c], rows 272B (16B-aligned)
    int bid = blockIdx.x;            // BQ*SWW blocks
    int b   = bid >> 9;
    int xi  = bid & (SWW - 1);
    int t   = threadIdx.x;

    const float4* T4 = (const float4*)T;
    const int* wrow = winner + ((size_t)(b * SWW + xi) << 9);
    float* orow = out + ((size_t)(b * CQ) * SWW + xi) * SWW;

    #pragma unroll 1
    for (int chunk = 0; chunk < 4; ++chunk) {
        int zi0 = chunk * 128;
        // gather: 128 cells x 16 float4 = 2048 float4, 4 iters
        #pragma unroll
        for (int iter = 0; iter < 4; ++iter) {
            int idx = iter * 512 + t;
            int cl  = idx >> 4;          // cell_local 0..127
            int c4  = idx & 15;
            int pid = wrow[zi0 + cl];
            float4 v = make_float4(0.f, 0.f, 0.f, 0.f);
            if (pid >= 0)
                v = T4[(size_t)(b * HWQ + (pid & (HWQ - 1))) * 16 + c4];
            *(float4*)&lds[cl][c4 * 4] = v;
        }
        __syncthreads();
        // write: 64 c x 128 zi, c-group of 4 per iter, coalesced over zi
        #pragma unroll
        for (int iter = 0; iter < 16; ++iter) {
            int zi = t & 127;
            int c  = iter * 4 + (t >> 7);
            orow[(size_t)c * (SWW * SWW) + zi0 + zi] = lds[zi][c];
        }
        __syncthreads();
    }
}

// Fallback emit (r13) if ws too small for T.
__global__ void __launch_bounds__(512) k_emit(const int* __restrict__ winner,
                                              const float* __restrict__ img,
                                              float* __restrict__ out) {
    int bid = blockIdx.x;
    int b   = bid >> 9;
    int xi  = bid & (SWW - 1);
    int zi  = threadIdx.x;

    int pid = winner[(b * SWW + xi) * SWW + zi];
    int src = -1;
    if (pid >= 0) src = b * (CQ * HWQ) + (pid & (HWQ - 1));

    float* op = out + ((size_t)(b * CQ) * SWW + xi) * SWW + zi;
    #pragma unroll 4
    for (int c = 0; c < CQ; ++c) {
        float val = (src >= 0) ? img[src + c * HWQ] : 0.0f;
        op[(size_t)c * SWW * SWW] = val;
    }
}

extern "C" void kernel_launch(void* const* d_in, const int* in_sizes, int n_in,
                              void* d_out, int out_size, void* d_ws, size_t ws_size,
                              hipStream_t stream) {
    const float* img   = (const float*)d_in[0];
    const float* ck    = (const float*)d_in[1];
    const float* depth = (const float*)d_in[2];
    const float* mpp   = (const float*)d_in[3];
    float* out = (float*)d_out;

    char* ws = (char*)d_ws;
    unsigned* seg    = (unsigned*)(ws + 256);                      // NSEG*4 = 4 MB
    int*      winner = (int*)(ws + 256 + (size_t)NSEG * 4);        // NSEG*4 = 4 MB
    int*      cellA  = (int*)(ws + 256 + (size_t)NSEG * 8);        // NPIX*4 = 1 MB
    float*    yA     = (float*)(ws + 256 + (size_t)NSEG * 8 + (size_t)NPIX * 4); // 1 MB
    size_t    offT   = 256 + (size_t)NSEG * 8 + (size_t)NPIX * 8;  // 16B-aligned
    float*    T      = (float*)(ws + offT);                        // 67 MB
    size_t    need   = offT + (size_t)NPIX * CQ * 4;

    k_init   <<<NSEG / 256, 256, 0, stream>>>(seg, winner);
    k_project<<<NPIX / 256, 256, 0, stream>>>(ck, depth, mpp, cellA, yA);
    k_segmin <<<NPIX / 256, 256, 0, stream>>>(cellA, yA, seg);
    k_winner <<<NPIX / 256, 256, 0, stream>>>(cellA, yA, seg, winner);
    if (ws_size >= need) {
        k_transpose<<<dim3(HWQ / 64, BQ), 256, 0, stream>>>(img, T);
        k_emit2    <<<BQ * SWW, 512, 0, stream>>>(winner, T, out);
    } else {
        k_emit     <<<BQ * SWW, 512, 0, stream>>>(winner, img, out);
    }
}

// Round 15
// 110.933 us; speedup vs baseline: 1.2828x; 1.1023x over previous
//
#include <hip/hip_runtime.h>
#include <cstdint>
#include <cstddef>

#define BQ   4
#define CQ   64
#define GH   128
#define GW   512
#define SWW  512
#define HALF 256
#define HWQ  (GH * GW)        // 65536
#define NPIX (BQ * HWQ)       // 262144
#define NSEG (BQ * SWW * SWW) // 1048576

typedef unsigned long long u64;

// Monotone order-preserving f32 -> u32 map: encoded compare == float compare.
__device__ __forceinline__ unsigned ord_encode(float f) {
    unsigned b = __float_as_uint(f);
    return (b & 0x80000000u) ? ~b : (b | 0x80000000u);
}

// R15: fused project+segmin+winner via ONE packed u64 atomicMin per kept
// pixel: key = (ord_encode(y) << 32) | ~pixel_id.
//   u64 min == lexicographic (min y, tie -> min ~id == max id == last-wins)
// -- bit-identical semantics to the r13/r14 passing chain.
// Projection chain (f32, reciprocal-multiply binning): DO NOT TOUCH.
__global__ void k_project(const float* __restrict__ ck,
                          const float* __restrict__ depth,
                          const float* __restrict__ mppp,
                          u64* __restrict__ seg) {
#pragma clang fp contract(off)
    int i = blockIdx.x * blockDim.x + threadIdx.x; // exactly NPIX threads
    int b   = i >> 16;       // / HWQ
    int rem = i & (HWQ - 1);
    int v   = rem >> 9;      // / GW
    int u   = rem & (GW - 1);

    const float* K = ck + b * 9;
    float K00 = K[0] * 0.5f;           // exact (250)
    float K02 = K[2] * 0.5f;           // exact (256)
    float K11 = K[4] * 0.5f;           // exact (250)
    float K12 = K[5] * 0.5f;           // exact (64)
    float Ki00 = 1.0f / K00;
    float Ki02 = (-K02) / K00;
    float Ki11 = 1.0f / K11;
    float Ki12 = (-K12) / K11;

    float d   = depth[i];
    float mpp = mppp[0];

    float tx = Ki00 * (float)u;
    asm volatile("" : "+v"(tx));
    float xw = tx + Ki02;
    float ty = Ki11 * (float)v;
    asm volatile("" : "+v"(ty));
    float yw = ty + Ki12;

    float x3 = (xw * d) * 1.2f;
    float y3 = (yw * d) * 1.2f;
    float z3 = d * 1.2f;

    float r = 1.0f / mpp;              // rn32(1/0.2f) == 5.0f exactly
    asm volatile("" : "+v"(r));
    float x = truncf(x3 * r);
    float z = truncf(z3 * r);

    bool kept = (x >= -(float)HALF) && (x <= (float)(HALF - 1)) &&
                (z >= -(float)HALF) && (z <= (float)(HALF - 1));

    if (kept) {
        int cell = b * (SWW * SWW) + ((int)x + HALF) * SWW + ((int)z + HALF);
        u64 key = ((u64)ord_encode(y3) << 32) | (u64)(~(unsigned)i);
        atomicMin(seg + cell, key);
    }
}

// img [b][c][p] -> T [b][p][c]: LDS tile transpose, 64c x 64p tiles,
// float4 on both global sides. 134 MB total, fully coalesced.
__global__ void __launch_bounds__(256) k_transpose(const float* __restrict__ img,
                                                   float* __restrict__ T) {
    __shared__ float lds[64][65];
    int b  = blockIdx.y;
    int p0 = blockIdx.x * 64;
    int t  = threadIdx.x;

    const float4* img4 = (const float4*)img;
    #pragma unroll
    for (int iter = 0; iter < 4; ++iter) {
        int idx = iter * 256 + t;          // 64c x 16p4
        int c   = idx >> 4;
        int p4  = idx & 15;
        float4 v = img4[((size_t)(b * CQ + c) * HWQ + p0) / 4 + p4];
        lds[c][p4 * 4 + 0] = v.x;
        lds[c][p4 * 4 + 1] = v.y;
        lds[c][p4 * 4 + 2] = v.z;
        lds[c][p4 * 4 + 3] = v.w;
    }
    __syncthreads();
    float4* T4 = (float4*)T;
    #pragma unroll
    for (int iter = 0; iter < 4; ++iter) {
        int idx = iter * 256 + t;          // 64p x 16c4
        int p   = idx >> 4;
        int c4  = idx & 15;
        float4 v;
        v.x = lds[c4 * 4 + 0][p];
        v.y = lds[c4 * 4 + 1][p];
        v.z = lds[c4 * 4 + 2][p];
        v.w = lds[c4 * 4 + 3][p];
        T4[(size_t)(b * HWQ + p0 + p) * 16 + c4] = v;
    }
}

// One block per (b, xi) row. Per 128-cell chunk: gather winner feature
// vectors as CONTIGUOUS 256B blocks from T (16 thr x float4 per cell),
// stage in LDS, then write out coalesced in [c][zi] order.
// Winner decode: seg != ~0 -> pid = ~(u32)seg.
__global__ void __launch_bounds__(512) k_emit2(const u64* __restrict__ seg,
                                               const float* __restrict__ T,
                                               float* __restrict__ out) {
    __shared__ float lds[128][68];   // [cell][c], rows 272B (16B-aligned)
    int bid = blockIdx.x;            // BQ*SWW blocks
    int b   = bid >> 9;
    int xi  = bid & (SWW - 1);
    int t   = threadIdx.x;

    const float4* T4 = (const float4*)T;
    const u64* srow = seg + ((size_t)(b * SWW + xi) << 9);
    float* orow = out + ((size_t)(b * CQ) * SWW + xi) * SWW;

    #pragma unroll 1
    for (int chunk = 0; chunk < 4; ++chunk) {
        int zi0 = chunk * 128;
        // gather: 128 cells x 16 float4 = 2048 float4, 4 iters
        #pragma unroll
        for (int iter = 0; iter < 4; ++iter) {
            int idx = iter * 512 + t;
            int cl  = idx >> 4;          // cell_local 0..127
            int c4  = idx & 15;
            u64 s   = srow[zi0 + cl];
            float4 v = make_float4(0.f, 0.f, 0.f, 0.f);
            if (s != ~0ULL) {
                int pid = (int)(~(unsigned)(s & 0xFFFFFFFFu));
                v = T4[(size_t)(b * HWQ + (pid & (HWQ - 1))) * 16 + c4];
            }
            *(float4*)&lds[cl][c4 * 4] = v;
        }
        __syncthreads();
        // write: 64 c x 128 zi, c-group of 4 per iter, coalesced over zi
        #pragma unroll
        for (int iter = 0; iter < 16; ++iter) {
            int zi = t & 127;
            int c  = iter * 4 + (t >> 7);
            orow[(size_t)c * (SWW * SWW) + zi0 + zi] = lds[zi][c];
        }
        __syncthreads();
    }
}

// Fallback emit (no T) if ws too small.
__global__ void __launch_bounds__(512) k_emit(const u64* __restrict__ seg,
                                              const float* __restrict__ img,
                                              float* __restrict__ out) {
    int bid = blockIdx.x;
    int b   = bid >> 9;
    int xi  = bid & (SWW - 1);
    int zi  = threadIdx.x;

    u64 s = seg[((size_t)(b * SWW + xi) << 9) + zi];
    int src = -1;
    if (s != ~0ULL) {
        int pid = (int)(~(unsigned)(s & 0xFFFFFFFFu));
        src = b * (CQ * HWQ) + (pid & (HWQ - 1));
    }

    float* op = out + ((size_t)(b * CQ) * SWW + xi) * SWW + zi;
    #pragma unroll 4
    for (int c = 0; c < CQ; ++c) {
        float val = (src >= 0) ? img[src + c * HWQ] : 0.0f;
        op[(size_t)c * SWW * SWW] = val;
    }
}

extern "C" void kernel_launch(void* const* d_in, const int* in_sizes, int n_in,
                              void* d_out, int out_size, void* d_ws, size_t ws_size,
                              hipStream_t stream) {
    const float* img   = (const float*)d_in[0];
    const float* ck    = (const float*)d_in[1];
    const float* depth = (const float*)d_in[2];
    const float* mpp   = (const float*)d_in[3];
    float* out = (float*)d_out;

    char* ws = (char*)d_ws;
    u64*   seg  = (u64*)(ws + 256);                     // NSEG*8 = 8 MB
    size_t offT = 256 + (size_t)NSEG * 8;               // 16B-aligned
    float* T    = (float*)(ws + offT);                  // 67 MB
    size_t need = offT + (size_t)NPIX * CQ * 4;

    // seg init: all bytes 0xFF == ~0ULL == (+inf key, empty)
    hipMemsetAsync(seg, 0xFF, (size_t)NSEG * 8, stream);
    k_project<<<NPIX / 256, 256, 0, stream>>>(ck, depth, mpp, seg);
    if (ws_size >= need) {
        k_transpose<<<dim3(HWQ / 64, BQ), 256, 0, stream>>>(img, T);
        k_emit2    <<<BQ * SWW, 512, 0, stream>>>(seg, T, out);
    } else {
        k_emit     <<<BQ * SWW, 512, 0, stream>>>(seg, img, out);
    }
}

// Round 16
// 97.551 us; speedup vs baseline: 1.4588x; 1.1372x over previous
//
#include <hip/hip_runtime.h>
#include <cstdint>
#include <cstddef>

#define BQ   4
#define CQ   64
#define GH   128
#define GW   512
#define SWW  512
#define HALF 256
#define HWQ  (GH * GW)        // 65536
#define NPIX (BQ * HWQ)       // 262144
#define NSEG (BQ * SWW * SWW) // 1048576

typedef unsigned long long u64;

// Monotone order-preserving f32 -> u32 map: encoded compare == float compare.
__device__ __forceinline__ unsigned ord_encode(float f) {
    unsigned b = __float_as_uint(f);
    return (b & 0x80000000u) ? ~b : (b | 0x80000000u);
}

// GOLDEN (r13): fused project+segmin+winner, ONE packed u64 atomicMin per
// kept pixel: key = (ord_encode(y) << 32) | ~pixel_id  (min y, tie->last id).
// f32 chain with reciprocal-multiply binning. DO NOT TOUCH.
__global__ void k_project(const float* __restrict__ ck,
                          const float* __restrict__ depth,
                          const float* __restrict__ mppp,
                          u64* __restrict__ seg) {
#pragma clang fp contract(off)
    int i = blockIdx.x * blockDim.x + threadIdx.x; // exactly NPIX threads
    int b   = i >> 16;       // / HWQ
    int rem = i & (HWQ - 1);
    int v   = rem >> 9;      // / GW
    int u   = rem & (GW - 1);

    const float* K = ck + b * 9;
    float K00 = K[0] * 0.5f;           // exact (250)
    float K02 = K[2] * 0.5f;           // exact (256)
    float K11 = K[4] * 0.5f;           // exact (250)
    float K12 = K[5] * 0.5f;           // exact (64)
    float Ki00 = 1.0f / K00;
    float Ki02 = (-K02) / K00;
    float Ki11 = 1.0f / K11;
    float Ki12 = (-K12) / K11;

    float d   = depth[i];
    float mpp = mppp[0];

    float tx = Ki00 * (float)u;
    asm volatile("" : "+v"(tx));
    float xw = tx + Ki02;
    float ty = Ki11 * (float)v;
    asm volatile("" : "+v"(ty));
    float yw = ty + Ki12;

    float x3 = (xw * d) * 1.2f;
    float y3 = (yw * d) * 1.2f;
    float z3 = d * 1.2f;

    float r = 1.0f / mpp;              // rn32(1/0.2f) == 5.0f exactly
    asm volatile("" : "+v"(r));
    float x = truncf(x3 * r);
    float z = truncf(z3 * r);

    bool kept = (x >= -(float)HALF) && (x <= (float)(HALF - 1)) &&
                (z >= -(float)HALF) && (z <= (float)(HALF - 1));

    if (kept) {
        int cell = b * (SWW * SWW) + ((int)x + HALF) * SWW + ((int)z + HALF);
        u64 key = ((u64)ord_encode(y3) << 32) | (u64)(~(unsigned)i);
        atomicMin(seg + cell, key);
    }
}

// img [b][c][p] -> T [b][p][c]: LDS tile transpose, 64c x 64p tiles,
// float4 both global sides. Normal stores (T should stay L2/L3-resident).
__global__ void __launch_bounds__(256) k_transpose(const float* __restrict__ img,
                                                   float* __restrict__ T) {
    __shared__ float lds[64][65];
    int b  = blockIdx.y;
    int p0 = blockIdx.x * 64;
    int t  = threadIdx.x;

    const float4* img4 = (const float4*)img;
    #pragma unroll
    for (int iter = 0; iter < 4; ++iter) {
        int idx = iter * 256 + t;          // 64c x 16p4
        int c   = idx >> 4;
        int p4  = idx & 15;
        float4 v = img4[((size_t)(b * CQ + c) * HWQ + p0) / 4 + p4];
        lds[c][p4 * 4 + 0] = v.x;
        lds[c][p4 * 4 + 1] = v.y;
        lds[c][p4 * 4 + 2] = v.z;
        lds[c][p4 * 4 + 3] = v.w;
    }
    __syncthreads();
    float4* T4 = (float4*)T;
    #pragma unroll
    for (int iter = 0; iter < 4; ++iter) {
        int idx = iter * 256 + t;          // 64p x 16c4
        int p   = idx >> 4;
        int c4  = idx & 15;
        float4 v;
        v.x = lds[c4 * 4 + 0][p];
        v.y = lds[c4 * 4 + 1][p];
        v.z = lds[c4 * 4 + 2][p];
        v.w = lds[c4 * 4 + 3][p];
        T4[(size_t)(b * HWQ + p0 + p) * 16 + c4] = v;
    }
}

// R16 emit: 8192 independent blocks (one 128-cell chunk each, single barrier).
// LDS row stride 69 floats: gather-write banks (5*cl+4*c4)%32 -> 2-way (free),
// read banks (5*zi+c)%32 -> full spread (was 8-way at stride 68).
// Output stores NONTEMPORAL: don't evict T from L2/L3.
__global__ void __launch_bounds__(512) k_emit2(const u64* __restrict__ seg,
                                               const float* __restrict__ T,
                                               float* __restrict__ out) {
    __shared__ float lds[128 * 69];
    int bid   = blockIdx.x;          // BQ*SWW*4
    int chunk = bid & 3;
    int row   = bid >> 2;
    int b     = row >> 9;
    int xi    = row & (SWW - 1);
    int zi0   = chunk * 128;
    int t     = threadIdx.x;

    const float4* T4 = (const float4*)T;
    const u64* srow = seg + ((size_t)row << 9);
    float* orow = out + ((size_t)(b * CQ) * SWW + xi) * SWW;

    // gather: 128 cells x 16 float4 = 2048, 4 iters
    #pragma unroll
    for (int iter = 0; iter < 4; ++iter) {
        int idx = iter * 512 + t;
        int cl  = idx >> 4;          // cell_local 0..127
        int c4  = idx & 15;
        u64 s   = srow[zi0 + cl];
        float4 v = make_float4(0.f, 0.f, 0.f, 0.f);
        if (s != ~0ULL) {
            int pid = (int)(~(unsigned)(s & 0xFFFFFFFFu));
            v = T4[(size_t)(b * HWQ + (pid & (HWQ - 1))) * 16 + c4];
        }
        float* dst = &lds[cl * 69 + c4 * 4];
        dst[0] = v.x; dst[1] = v.y; dst[2] = v.z; dst[3] = v.w;
    }
    __syncthreads();
    // write: 64 c x 128 zi, coalesced over zi, nontemporal
    #pragma unroll
    for (int iter = 0; iter < 16; ++iter) {
        int zi = t & 127;
        int c  = iter * 4 + (t >> 7);
        __builtin_nontemporal_store(lds[zi * 69 + c],
                                    &orow[(size_t)c * (SWW * SWW) + zi0 + zi]);
    }
}

// Fallback emit (no T) if ws too small.
__global__ void __launch_bounds__(512) k_emit(const u64* __restrict__ seg,
                                              const float* __restrict__ img,
                                              float* __restrict__ out) {
    int bid = blockIdx.x;
    int b   = bid >> 9;
    int xi  = bid & (SWW - 1);
    int zi  = threadIdx.x;

    u64 s = seg[((size_t)(b * SWW + xi) << 9) + zi];
    int src = -1;
    if (s != ~0ULL) {
        int pid = (int)(~(unsigned)(s & 0xFFFFFFFFu));
        src = b * (CQ * HWQ) + (pid & (HWQ - 1));
    }

    float* op = out + ((size_t)(b * CQ) * SWW + xi) * SWW + zi;
    #pragma unroll 4
    for (int c = 0; c < CQ; ++c) {
        float val = (src >= 0) ? img[src + c * HWQ] : 0.0f;
        __builtin_nontemporal_store(val, &op[(size_t)c * SWW * SWW]);
    }
}

extern "C" void kernel_launch(void* const* d_in, const int* in_sizes, int n_in,
                              void* d_out, int out_size, void* d_ws, size_t ws_size,
                              hipStream_t stream) {
    const float* img   = (const float*)d_in[0];
    const float* ck    = (const float*)d_in[1];
    const float* depth = (const float*)d_in[2];
    const float* mpp   = (const float*)d_in[3];
    float* out = (float*)d_out;

    char* ws = (char*)d_ws;
    u64*   seg  = (u64*)(ws + 256);                     // NSEG*8 = 8 MB
    size_t offT = 256 + (size_t)NSEG * 8;               // 16B-aligned
    float* T    = (float*)(ws + offT);                  // 67 MB
    size_t need = offT + (size_t)NPIX * CQ * 4;

    // seg init: all bytes 0xFF == ~0ULL == (+inf key, empty)
    hipMemsetAsync(seg, 0xFF, (size_t)NSEG * 8, stream);
    k_project<<<NPIX / 256, 256, 0, stream>>>(ck, depth, mpp, seg);
    if (ws_size >= need) {
        k_transpose<<<dim3(HWQ / 64, BQ), 256, 0, stream>>>(img, T);
        k_emit2    <<<BQ * SWW * 4, 512, 0, stream>>>(seg, T, out);
    } else {
        k_emit     <<<BQ * SWW, 512, 0, stream>>>(seg, img, out);
    }
}